// Round 2
// baseline (795.846 us; speedup 1.0000x reference)
//
#include <hip/hip_runtime.h>
#include <math.h>

#define NEG_SLOPE 0.1f

typedef unsigned short u16;
typedef unsigned int u32;
typedef _Float16 f16;
typedef f16 f16x2 __attribute__((ext_vector_type(2)));
typedef f16 f16x8 __attribute__((ext_vector_type(8)));
typedef float f32x4 __attribute__((ext_vector_type(4)));

// async 16B global->LDS (lds dest = wave-uniform base + lane*16)
#define GLLDS16(g, l) __builtin_amdgcn_global_load_lds( \
    (const __attribute__((address_space(1))) void*)(g), \
    (__attribute__((address_space(3))) void*)(l), 16, 0, 0)

struct P {
    const float* features; const int* src; const int* dst; const float* w;
    const float* W1; const float* al1; const float* ar1;
    const float* W2; const float* al2; const float* ar2;
    const float* W3; const float* bout; float* out;
    int* cnt; int* fill; int* ctr; int* bar; int* start; int2* edge_s;
    u16* fth; float* el; float* er; u16* xcat;
    u16* b1; u16* b2; u16* b3;
    int N, E, Mpad;
};

// ---------------- device-scope grid barrier (blocks co-resident by construction) ----
// bar slots are 64B apart; zeroed by the memset node before this kernel each replay.

__device__ __forceinline__ void gsync(int* bar, int slot) {
    __syncthreads();
    if (threadIdx.x == 0) {
        __threadfence();  // release prior writes to device scope
        int* a = &bar[slot * 16];
        int prev = __hip_atomic_fetch_add(a, 1, __ATOMIC_ACQ_REL, __HIP_MEMORY_SCOPE_AGENT);
        if (prev == (int)gridDim.x - 1) {
            __hip_atomic_store(a + 1, 1, __ATOMIC_RELEASE, __HIP_MEMORY_SCOPE_AGENT);
        } else {
            while (!__hip_atomic_load(a + 1, __ATOMIC_ACQUIRE, __HIP_MEMORY_SCOPE_AGENT))
                __builtin_amdgcn_s_sleep(4);
        }
    }
    __syncthreads();
}

// ---------------- weight-panel cast (blocked, conflict-free layout) ----------------
// per kt, per 16-col block nt: u16 index = nt*512 + kg*128 + col*8 + k_in
// -> MFMA B-fragment read of lane l is a LINEAR 16B read at (nt*512 + l*8)*2.

__device__ __forceinline__ void cast_panel(const float* __restrict__ W,
                                           const float* __restrict__ al,
                                           const float* __restrict__ ar,
                                           u16* __restrict__ bp, int t, int NC) {
    int per_kt = NC * 16;          // u32 per kt
    int kt = t / per_kt;
    int rem = t - kt * per_kt;
    int nt = rem >> 8;             // 256 u32 per 16-col block
    int w32 = rem & 255;
    int kg = w32 >> 6;
    int col = (w32 >> 2) & 15;
    int kp = (w32 & 3) * 2;
    int n = nt * 16 + col;
    int k = kt * 32 + kg * 8 + kp;
    float v0 = 0.f, v1 = 0.f;
    if (n < 128) {
        v0 = W[(size_t)k * 128 + n];
        v1 = W[(size_t)(k + 1) * 128 + n];
    } else if (n < 136) {
        const float* av = (n < 132) ? al : ar;
        if (av) {
            int h = (n < 132) ? (n - 128) : (n - 132);
            float s0 = 0.f, s1 = 0.f;
            for (int d = 0; d < 32; d++) {
                float a = av[h * 32 + d];
                s0 += W[(size_t)k * 128 + h * 32 + d] * a;
                s1 += W[(size_t)(k + 1) * 128 + h * 32 + d] * a;
            }
            v0 = s0; v1 = s1;
        }
    }
    f16x2 pk;
    pk.x = (f16)v0; pk.y = (f16)v1;
    *(f16x2*)&((u32*)bp)[t] = pk;
}

// ---------------- phase bodies (all grid-stride; shared by fused + fallback) --------

__device__ void phase_hist(const P& p) {
    int gsz = gridDim.x * 256;
    for (int t = blockIdx.x * 256 + threadIdx.x; t < p.E; t += gsz) {
        atomicAdd(&p.cnt[p.dst[t]], 1);
        // b1: 18432 u32, b2: 9216, b3: 18432 (all 144-col panels)
        if (t < 18432) cast_panel(p.W1, p.al1, p.ar1, p.b1, t, 144);
        else if (t < 27648) cast_panel(p.W2, p.al2, p.ar2, p.b2, t - 18432, 144);
        else if (t < 46080) cast_panel(p.W3, nullptr, nullptr, p.b3, t - 27648, 144);
    }
}

__device__ void phase_assign(const P& p, char* sh) {
    int* s = (int*)sh;
    int* basep = s + 256;
    int t = threadIdx.x;
    int chunks = (p.N + 255) >> 8;
    for (int c = blockIdx.x; c < chunks; c += gridDim.x) {
        int i = c * 256 + t;
        int v = (i < p.N) ? p.cnt[i] : 0;
        s[t] = v;
        __syncthreads();
        int incl = v;
        for (int off = 1; off < 256; off <<= 1) {
            int add = (t >= off) ? s[t - off] : 0;
            __syncthreads();
            incl += add;
            s[t] = incl;
            __syncthreads();
        }
        if (t == 255) *basep = atomicAdd(p.ctr, incl);
        __syncthreads();
        if (i < p.N) p.start[i] = *basep + incl - v;
        __syncthreads();
    }
}

__device__ void phase_scatter(const P& p) {
    int gsz = gridDim.x * 256;
    for (int e = blockIdx.x * 256 + threadIdx.x; e < p.E; e += gsz) {
        int d = p.dst[e];
        int pos = atomicAdd(&p.fill[d], 1);
        p.edge_s[p.start[d] + pos] = make_int2(p.src[e], __float_as_int(p.w[e]));
    }
}

// fp16 MFMA GEMM tile loop: C = A[M,K](lda) @ B(+bias); blocked LDS, zero bank conflicts.
__device__ void gemm_core(const void* Av, int a_is_f16, int lda, const u16* Bp,
                          const float* bias, float* Cf, u16* Ch,
                          float* el, float* er, int M, int K, char* shmem) {
    u16* As = (u16*)shmem;           // 2048 u16 (64 rows x 32 k, blocked)
    u16* Bs = (u16*)(shmem + 4096);  // 9*512 u16 (144 cols x 32 k, blocked)
    int tid = threadIdx.x;
    int wv = tid >> 6, lane = tid & 63;
    int mrow = lane & 15;
    int tiles = (M + 63) >> 6;
    for (int t = blockIdx.x; t < tiles; t += gridDim.x) {
        int row0 = t * 64;
        f32x4 acc[9];
#pragma unroll
        for (int nt = 0; nt < 9; nt++) acc[nt] = (f32x4){0.f, 0.f, 0.f, 0.f};
        for (int k0 = 0; k0 < K; k0 += 32) {
            int kt = k0 >> 5;
#pragma unroll
            for (int i = 0; i < 3; i++) {  // 576 B-chunks of 16B over 256 threads
                int c = tid + i * 256;
                if (c < 576)
                    GLLDS16(Bp + (size_t)kt * 4608 + (size_t)c * 8, &Bs[c * 8]);
            }
            int c = tid;
            int rblk = c >> 6, kg = (c >> 4) & 3, rr = c & 15;
            if (a_is_f16) {
                const u16* Ah = (const u16*)Av;
                GLLDS16(Ah + (size_t)(row0 + rblk * 16 + rr) * lda + k0 + kg * 8,
                        &As[c * 8]);
            } else {
                const float* Af = (const float*)Av;
                int row = row0 + rblk * 16 + rr;
                if (row > M - 1) row = M - 1;  // clamp; pad rows discarded in epilogue
                const float* ap = &Af[(size_t)row * lda + k0 + kg * 8];
                float4 v0 = *(const float4*)ap;
                float4 v1 = *(const float4*)(ap + 4);
                f16x8 pk;
                pk[0] = (f16)v0.x; pk[1] = (f16)v0.y; pk[2] = (f16)v0.z; pk[3] = (f16)v0.w;
                pk[4] = (f16)v1.x; pk[5] = (f16)v1.y; pk[6] = (f16)v1.z; pk[7] = (f16)v1.w;
                *(f16x8*)&As[c * 8] = pk;
            }
            __syncthreads();
            f16x8 ah = *(const f16x8*)&As[wv * 512 + lane * 8];  // linear, conflict-free
#pragma unroll
            for (int nt = 0; nt < 9; nt++) {
                f16x8 bh = *(const f16x8*)&Bs[nt * 512 + lane * 8];
                acc[nt] = __builtin_amdgcn_mfma_f32_16x16x32_f16(ah, bh, acc[nt], 0, 0, 0);
            }
            __syncthreads();
        }
        // epilogue: C/D layout col=lane&15, row=(lane>>4)*4+reg
        int rbase = row0 + wv * 16 + (lane >> 4) * 4;
#pragma unroll
        for (int nt = 0; nt < 8; nt++) {
            int col = nt * 16 + mrow;
            float bv = bias ? bias[col] : 0.f;
            f32x4 v = acc[nt];
#pragma unroll
            for (int reg = 0; reg < 4; reg++) {
                int r2 = rbase + reg;
                if (r2 < M) {
                    float val = v[reg] + bv;
                    if (Cf) Cf[(size_t)r2 * 128 + col] = val;
                    if (Ch) *(f16*)&Ch[(size_t)r2 * 128 + col] = (f16)val;
                }
            }
        }
        if (el) {  // cols 128..135: el heads 0-3, er heads 0-3
            f32x4 v = acc[8];
#pragma unroll
            for (int reg = 0; reg < 4; reg++) {
                int r2 = rbase + reg;
                if (r2 < M) {
                    if (mrow < 4) el[r2 * 4 + mrow] = v[reg];
                    else if (mrow < 8) er[r2 * 4 + (mrow - 4)] = v[reg];
                }
            }
        }
    }
}

__device__ void gemm_sel(const P& p, int which, char* sh) {
    if (which == 1)
        gemm_core(p.features, 0, 256, p.b1, nullptr, nullptr, p.fth, p.el, p.er,
                  p.N, 256, sh);
    else if (which == 2)
        gemm_core(p.xcat, 1, 256, p.b2, nullptr, nullptr, p.fth, p.el, p.er,
                  p.N, 128, sh);
    else
        gemm_core(p.xcat, 1, 256, p.b3, p.bout, p.out, nullptr, nullptr, nullptr,
                  p.N, 256, sh);
}

__device__ __forceinline__ float lrelu(float x) {
    return x > 0.f ? x : NEG_SLOPE * x;
}

__device__ void phase_agg(const P& p, int ooff, char* sh) {
    float4* sA = (float4*)sh;          // [wave*64 + edge] normalized alphas
    int* sS = (int*)(sh + 4096);       // [wave*64 + edge] src node
    const u32* fth2 = (const u32*)p.fth;
    const float4* el4 = (const float4*)p.el;
    const float4* er4 = (const float4*)p.er;
    int wv = threadIdx.x >> 6;
    int lane = threadIdx.x & 63;
    int head = lane >> 4;
    int ngroups = (p.N + 3) >> 2;
    for (int g = blockIdx.x; g < ngroups; g += gridDim.x) {
        int n = g * 4 + wv;
        if (n >= p.N) continue;
        int r0 = p.start[n], deg = p.cnt[n];
        u16* op = &p.xcat[(size_t)n * 256 + ooff + 2 * lane];
        if (deg == 0) {
            *(u32*)op = 0;
            continue;
        }
        float4 ern = er4[n];  // wave-uniform
        float acc0 = 0.f, acc1 = 0.f;
        if (deg <= 64) {
            // lane i owns edge i. Logits tiny (|l| < ~2): softmax w/o max-shift is safe.
            float4 a = make_float4(0.f, 0.f, 0.f, 0.f);
            int s = 0;
            if (lane < deg) {
                int2 ep = p.edge_s[r0 + lane];
                s = ep.x;
                float we = __int_as_float(ep.y);
                float4 e = el4[s];
                a.x = __expf(we * lrelu(e.x + ern.x));
                a.y = __expf(we * lrelu(e.y + ern.y));
                a.z = __expf(we * lrelu(e.z + ern.z));
                a.w = __expf(we * lrelu(e.w + ern.w));
            }
            float4 sm = a;
            for (int m = 1; m < deg; m <<= 1) {  // truncated butterfly
                sm.x += __shfl_xor(sm.x, m);
                sm.y += __shfl_xor(sm.y, m);
                sm.z += __shfl_xor(sm.z, m);
                sm.w += __shfl_xor(sm.w, m);
            }
            a.x *= __builtin_amdgcn_rcpf(sm.x);
            a.y *= __builtin_amdgcn_rcpf(sm.y);
            a.z *= __builtin_amdgcn_rcpf(sm.z);
            a.w *= __builtin_amdgcn_rcpf(sm.w);
            sA[wv * 64 + lane] = a;
            sS[wv * 64 + lane] = s;
            const float* sAf = (const float*)&sA[wv * 64];
            const int* sSp = &sS[wv * 64];
            int i = 0;
            for (; i + 8 <= deg; i += 8) {  // 8 independent gathers in flight
                float wg[8];
                u32 pp[8];
#pragma unroll
                for (int j = 0; j < 8; j++) {
                    wg[j] = sAf[(i + j) * 4 + head];
                    pp[j] = fth2[(size_t)sSp[i + j] * 64 + lane];
                }
#pragma unroll
                for (int j = 0; j < 8; j++) {
                    f16x2 hp = *(const f16x2*)&pp[j];
                    acc0 += wg[j] * (float)hp.x;
                    acc1 += wg[j] * (float)hp.y;
                }
            }
            for (; i < deg; i++) {
                float wgt = sAf[i * 4 + head];
                u32 pv = fth2[(size_t)sSp[i] * 64 + lane];
                f16x2 hp = *(const f16x2*)&pv;
                acc0 += wgt * (float)hp.x;
                acc1 += wgt * (float)hp.y;
            }
        } else {
            // deg > 64 (rare): lane-strided, keep max-shift
            float4 mx = make_float4(-INFINITY, -INFINITY, -INFINITY, -INFINITY);
            for (int i = lane; i < deg; i += 64) {
                int2 ep = p.edge_s[r0 + i];
                float we = __int_as_float(ep.y);
                float4 e = el4[ep.x];
                mx.x = fmaxf(mx.x, we * lrelu(e.x + ern.x));
                mx.y = fmaxf(mx.y, we * lrelu(e.y + ern.y));
                mx.z = fmaxf(mx.z, we * lrelu(e.z + ern.z));
                mx.w = fmaxf(mx.w, we * lrelu(e.w + ern.w));
            }
            for (int m = 32; m >= 1; m >>= 1) {
                mx.x = fmaxf(mx.x, __shfl_xor(mx.x, m));
                mx.y = fmaxf(mx.y, __shfl_xor(mx.y, m));
                mx.z = fmaxf(mx.z, __shfl_xor(mx.z, m));
                mx.w = fmaxf(mx.w, __shfl_xor(mx.w, m));
            }
            float4 sm = make_float4(0.f, 0.f, 0.f, 0.f);
            for (int i = lane; i < deg; i += 64) {
                int2 ep = p.edge_s[r0 + i];
                float we = __int_as_float(ep.y);
                float4 e = el4[ep.x];
                sm.x += __expf(we * lrelu(e.x + ern.x) - mx.x);
                sm.y += __expf(we * lrelu(e.y + ern.y) - mx.y);
                sm.z += __expf(we * lrelu(e.z + ern.z) - mx.z);
                sm.w += __expf(we * lrelu(e.w + ern.w) - mx.w);
            }
            for (int m = 32; m >= 1; m >>= 1) {
                sm.x += __shfl_xor(sm.x, m);
                sm.y += __shfl_xor(sm.y, m);
                sm.z += __shfl_xor(sm.z, m);
                sm.w += __shfl_xor(sm.w, m);
            }
            float4 inv;
            inv.x = 1.f / sm.x; inv.y = 1.f / sm.y;
            inv.z = 1.f / sm.z; inv.w = 1.f / sm.w;
            for (int i = 0; i < deg; i++) {
                int2 ep = p.edge_s[r0 + i];
                int si = ep.x;
                float we = __int_as_float(ep.y);
                float4 e = el4[si];
                float ax = __expf(we * lrelu(e.x + ern.x) - mx.x) * inv.x;
                float ay = __expf(we * lrelu(e.y + ern.y) - mx.y) * inv.y;
                float az = __expf(we * lrelu(e.z + ern.z) - mx.z) * inv.z;
                float aw = __expf(we * lrelu(e.w + ern.w) - mx.w) * inv.w;
                float wgt = head == 0 ? ax : (head == 1 ? ay : (head == 2 ? az : aw));
                u32 pv = fth2[(size_t)si * 64 + lane];
                f16x2 hp = *(const f16x2*)&pv;
                acc0 += wgt * (float)hp.x;
                acc1 += wgt * (float)hp.y;
            }
        }
        f16x2 hv;
        hv.x = (f16)fmaxf(acc0, 0.f);
        hv.y = (f16)fmaxf(acc1, 0.f);
        *(f16x2*)op = hv;
    }
}

// ---------------- fused persistent kernel: 7 phases, 6 grid syncs ----------------

__global__ __launch_bounds__(256, 4) void k_fused(P p) {
    alignas(16) __shared__ char sh[13312];
    phase_hist(p);                  // hist atomics + all weight-panel casts
    gsync(p.bar, 0);
    phase_assign(p, sh);            // segment starts (order-free)
    gsync(p.bar, 1);
    phase_scatter(p);               // edge scatter (independent of gemm1)
    gemm_sel(p, 1, sh);             // fth/el/er = f(features @ W1)
    gsync(p.bar, 2);
    phase_agg(p, 0, sh);            // x1 -> xcat[:, 0:128]
    gsync(p.bar, 3);
    gemm_sel(p, 2, sh);             // fth/el/er = f(x1 @ W2)
    gsync(p.bar, 4);
    phase_agg(p, 128, sh);          // x2 -> xcat[:, 128:256]
    gsync(p.bar, 5);
    gemm_sel(p, 3, sh);             // out = xcat @ Wout + bout
}

// ---------------- fallback wrappers (multi-dispatch path) ----------------

__global__ __launch_bounds__(256) void k_p1(P p) { phase_hist(p); }
__global__ __launch_bounds__(256) void k_assign(P p) {
    alignas(16) __shared__ char sh[2048];
    phase_assign(p, sh);
}
__global__ __launch_bounds__(256) void k_scatter(P p) { phase_scatter(p); }
__global__ __launch_bounds__(256) void k_gemm(P p, int which) {
    alignas(16) __shared__ char sh[13312];
    gemm_sel(p, which, sh);
}
__global__ __launch_bounds__(256) void k_agg(P p, int ooff) {
    alignas(16) __shared__ char sh[8192];
    phase_agg(p, ooff, sh);
}

// ---------------- launch ----------------

extern "C" void kernel_launch(void* const* d_in, const int* in_sizes, int n_in,
                              void* d_out, int out_size, void* d_ws, size_t ws_size,
                              hipStream_t stream) {
    P p;
    p.features = (const float*)d_in[0];
    p.src = (const int*)d_in[1];
    p.dst = (const int*)d_in[2];
    p.w = (const float*)d_in[3];
    p.W1 = (const float*)d_in[4];
    p.al1 = (const float*)d_in[5];
    p.ar1 = (const float*)d_in[6];
    p.W2 = (const float*)d_in[7];
    p.al2 = (const float*)d_in[8];
    p.ar2 = (const float*)d_in[9];
    p.W3 = (const float*)d_in[10];
    p.bout = (const float*)d_in[11];
    p.out = (float*)d_out;

    p.N = in_sizes[0] / 256;                // 50000
    p.E = in_sizes[1];                      // 400000
    p.Mpad = ((p.N + 127) / 128) * 128;     // 50048

    char* ws = (char*)d_ws;
    size_t off = 0;
    auto alloc = [&](size_t bytes) -> void* {
        void* q = ws + off;
        off = (off + bytes + 255) & ~(size_t)255;
        return q;
    };
    size_t Nr = ((size_t)p.N * 4 + 255) & ~(size_t)255;
    p.cnt = (int*)alloc(2 * Nr + 1024);                 // cnt + fill + ctr + bar
    p.fill = (int*)((char*)p.cnt + Nr);
    p.ctr = (int*)((char*)p.cnt + 2 * Nr);
    p.bar = p.ctr + 64;                                 // 6 slots x 64B
    p.start = (int*)alloc((size_t)p.N * 4);
    p.edge_s = (int2*)alloc((size_t)p.E * 8);
    p.fth = (u16*)alloc((size_t)p.Mpad * 128 * 2);
    p.el = (float*)alloc((size_t)p.N * 4 * 4);
    p.er = (float*)alloc((size_t)p.N * 4 * 4);
    p.xcat = (u16*)alloc((size_t)p.Mpad * 256 * 2);
    p.b1 = (u16*)alloc((size_t)18432 * 4);
    p.b2 = (u16*)alloc((size_t)9216 * 4);
    p.b3 = (u16*)alloc((size_t)18432 * 4);
    (void)ws_size; (void)n_in; (void)out_size;

    hipMemsetAsync(p.cnt, 0, 2 * Nr + 1024, stream);    // also zeroes barrier slots

    static int s_grid = -2;
    if (s_grid == -2) {
        int b = 0;
        hipError_t e = hipOccupancyMaxActiveBlocksPerMultiprocessor(&b, k_fused, 256, 0);
        // MI355X: 256 CUs. Co-residency guaranteed by occupancy result.
        s_grid = (e == hipSuccess && b >= 1) ? (b * 256 < 1024 ? b * 256 : 1024) : 0;
    }

    if (s_grid > 0) {
        k_fused<<<s_grid, 256, 0, stream>>>(p);
    } else {
        int eb = (p.E + 255) / 256;
        int cb = (p.N + 255) / 256;
        int gb = p.Mpad / 64;
        k_p1<<<eb, 256, 0, stream>>>(p);
        k_assign<<<cb, 256, 0, stream>>>(p);
        k_scatter<<<eb, 256, 0, stream>>>(p);
        k_gemm<<<gb, 256, 0, stream>>>(p, 1);
        k_agg<<<2048, 256, 0, stream>>>(p, 0);
        k_gemm<<<gb, 256, 0, stream>>>(p, 2);
        k_agg<<<2048, 256, 0, stream>>>(p, 128);
        k_gemm<<<gb, 256, 0, stream>>>(p, 3);
    }
}

// Round 4
// 592.834 us; speedup vs baseline: 1.3424x; 1.3424x over previous
//
#include <hip/hip_runtime.h>
#include <math.h>

#define NEG_SLOPE 0.1f

typedef unsigned short u16;
typedef unsigned int u32;
typedef _Float16 f16;
typedef f16 f16x2 __attribute__((ext_vector_type(2)));
typedef f16 f16x8 __attribute__((ext_vector_type(8)));
typedef float f32x4 __attribute__((ext_vector_type(4)));

// async 16B global->LDS (lds dest = wave-uniform base + lane*16)
#define GLLDS16(g, l) __builtin_amdgcn_global_load_lds( \
    (const __attribute__((address_space(1))) void*)(g), \
    (__attribute__((address_space(3))) void*)(l), 16, 0, 0)

struct P {
    const float* features; const int* src; const int* dst; const float* w;
    const float* W1; const float* al1; const float* ar1;
    const float* W2; const float* al2; const float* ar2;
    const float* W3; const float* bout; float* out;
    int* cnt; int* fill; int* ctr; int* bar; int* start; int2* edge_s;
    u16* fth; float* el; float* er; u16* xcat;
    u16* b1; u16* b2; u16* b3;
    int N, E, Mpad;
};

// ---------------- cache-benign device-scope grid barrier ----------------
// Arrival: RELEASE fetch_add (writeback only — no L2 eviction).
// Wait: RELAXED spin (NO buffer_inv per poll!), then ONE acquire fence after
// the flag flips. The acquire-per-poll variant invalidated the XCD L2 millions
// of times while stragglers computed (round-2: 244 GB/s, FETCH 150 MB, 1119 us).
// Count and flag on separate 64B lines.

__device__ __forceinline__ void gsync(int* bar, int slot) {
    __syncthreads();
    if (threadIdx.x == 0) {
        int* cntp = &bar[slot * 32];
        int* flagp = &bar[slot * 32 + 16];
        int prev = __hip_atomic_fetch_add(cntp, 1, __ATOMIC_RELEASE,
                                          __HIP_MEMORY_SCOPE_AGENT);
        if (prev == (int)gridDim.x - 1) {
            // last arrival: acquire everyone's writes, then publish
            __builtin_amdgcn_fence(__ATOMIC_ACQUIRE, "agent");
            __hip_atomic_store(flagp, 1, __ATOMIC_RELEASE, __HIP_MEMORY_SCOPE_AGENT);
        } else {
            while (!__hip_atomic_load(flagp, __ATOMIC_RELAXED, __HIP_MEMORY_SCOPE_AGENT))
                __builtin_amdgcn_s_sleep(8);
            __builtin_amdgcn_fence(__ATOMIC_ACQUIRE, "agent");
        }
    }
    __syncthreads();
}

// ---------------- weight-panel cast (blocked, conflict-free layout) ----------------
// per kt, per 16-col block nt: u16 index = nt*512 + kg*128 + col*8 + k_in
// -> MFMA B-fragment read of lane l is a LINEAR 16B read at (nt*512 + l*8)*2.

__device__ __forceinline__ void cast_panel(const float* __restrict__ W,
                                           const float* __restrict__ al,
                                           const float* __restrict__ ar,
                                           u16* __restrict__ bp, int t, int NC) {
    int per_kt = NC * 16;          // u32 per kt
    int kt = t / per_kt;
    int rem = t - kt * per_kt;
    int nt = rem >> 8;             // 256 u32 per 16-col block
    int w32 = rem & 255;
    int kg = w32 >> 6;
    int col = (w32 >> 2) & 15;
    int kp = (w32 & 3) * 2;
    int n = nt * 16 + col;
    int k = kt * 32 + kg * 8 + kp;
    float v0 = 0.f, v1 = 0.f;
    if (n < 128) {
        v0 = W[(size_t)k * 128 + n];
        v1 = W[(size_t)(k + 1) * 128 + n];
    } else if (n < 136) {
        const float* av = (n < 132) ? al : ar;
        if (av) {
            int h = (n < 132) ? (n - 128) : (n - 132);
            float s0 = 0.f, s1 = 0.f;
            for (int d = 0; d < 32; d++) {
                float a = av[h * 32 + d];
                s0 += W[(size_t)k * 128 + h * 32 + d] * a;
                s1 += W[(size_t)(k + 1) * 128 + h * 32 + d] * a;
            }
            v0 = s0; v1 = s1;
        }
    }
    f16x2 pk;
    pk.x = (f16)v0; pk.y = (f16)v1;
    *(f16x2*)&((u32*)bp)[t] = pk;
}

// ---------------- phase bodies (all grid-stride; shared by fused + fallback) --------

__device__ void phase_hist(const P& p) {
    int gsz = gridDim.x * 256;
    for (int t = blockIdx.x * 256 + threadIdx.x; t < p.E; t += gsz) {
        atomicAdd(&p.cnt[p.dst[t]], 1);
        // b1: 18432 u32, b2: 9216, b3: 18432 (all 144-col panels)
        if (t < 18432) cast_panel(p.W1, p.al1, p.ar1, p.b1, t, 144);
        else if (t < 27648) cast_panel(p.W2, p.al2, p.ar2, p.b2, t - 18432, 144);
        else if (t < 46080) cast_panel(p.W3, nullptr, nullptr, p.b3, t - 27648, 144);
    }
}

__device__ void phase_assign(const P& p, char* sh) {
    int* s = (int*)sh;
    int* basep = s + 256;
    int t = threadIdx.x;
    int chunks = (p.N + 255) >> 8;
    for (int c = blockIdx.x; c < chunks; c += gridDim.x) {
        int i = c * 256 + t;
        int v = (i < p.N) ? p.cnt[i] : 0;
        s[t] = v;
        __syncthreads();
        int incl = v;
        for (int off = 1; off < 256; off <<= 1) {
            int add = (t >= off) ? s[t - off] : 0;
            __syncthreads();
            incl += add;
            s[t] = incl;
            __syncthreads();
        }
        if (t == 255) *basep = atomicAdd(p.ctr, incl);
        __syncthreads();
        if (i < p.N) p.start[i] = *basep + incl - v;
        __syncthreads();
    }
}

__device__ void phase_scatter(const P& p) {
    int gsz = gridDim.x * 256;
    for (int e = blockIdx.x * 256 + threadIdx.x; e < p.E; e += gsz) {
        int d = p.dst[e];
        int pos = atomicAdd(&p.fill[d], 1);
        p.edge_s[p.start[d] + pos] = make_int2(p.src[e], __float_as_int(p.w[e]));
    }
}

// fp16 MFMA GEMM tile loop: C = A[M,K](lda) @ B(+bias); blocked LDS, zero bank conflicts.
__device__ void gemm_core(const void* Av, int a_is_f16, int lda, const u16* Bp,
                          const float* bias, float* Cf, u16* Ch,
                          float* el, float* er, int M, int K, char* shmem) {
    u16* As = (u16*)shmem;           // 2048 u16 (64 rows x 32 k, blocked)
    u16* Bs = (u16*)(shmem + 4096);  // 9*512 u16 (144 cols x 32 k, blocked)
    int tid = threadIdx.x;
    int wv = tid >> 6, lane = tid & 63;
    int mrow = lane & 15;
    int tiles = (M + 63) >> 6;
    for (int t = blockIdx.x; t < tiles; t += gridDim.x) {
        int row0 = t * 64;
        f32x4 acc[9];
#pragma unroll
        for (int nt = 0; nt < 9; nt++) acc[nt] = (f32x4){0.f, 0.f, 0.f, 0.f};
        for (int k0 = 0; k0 < K; k0 += 32) {
            int kt = k0 >> 5;
#pragma unroll
            for (int i = 0; i < 3; i++) {  // 576 B-chunks of 16B over 256 threads
                int c = tid + i * 256;
                if (c < 576)
                    GLLDS16(Bp + (size_t)kt * 4608 + (size_t)c * 8, &Bs[c * 8]);
            }
            int c = tid;
            int rblk = c >> 6, kg = (c >> 4) & 3, rr = c & 15;
            if (a_is_f16) {
                const u16* Ah = (const u16*)Av;
                GLLDS16(Ah + (size_t)(row0 + rblk * 16 + rr) * lda + k0 + kg * 8,
                        &As[c * 8]);
            } else {
                const float* Af = (const float*)Av;
                int row = row0 + rblk * 16 + rr;
                if (row > M - 1) row = M - 1;  // clamp; pad rows discarded in epilogue
                const float* ap = &Af[(size_t)row * lda + k0 + kg * 8];
                float4 v0 = *(const float4*)ap;
                float4 v1 = *(const float4*)(ap + 4);
                f16x8 pk;
                pk[0] = (f16)v0.x; pk[1] = (f16)v0.y; pk[2] = (f16)v0.z; pk[3] = (f16)v0.w;
                pk[4] = (f16)v1.x; pk[5] = (f16)v1.y; pk[6] = (f16)v1.z; pk[7] = (f16)v1.w;
                *(f16x8*)&As[c * 8] = pk;
            }
            __syncthreads();
            f16x8 ah = *(const f16x8*)&As[wv * 512 + lane * 8];  // linear, conflict-free
#pragma unroll
            for (int nt = 0; nt < 9; nt++) {
                f16x8 bh = *(const f16x8*)&Bs[nt * 512 + lane * 8];
                acc[nt] = __builtin_amdgcn_mfma_f32_16x16x32_f16(ah, bh, acc[nt], 0, 0, 0);
            }
            __syncthreads();
        }
        // epilogue: C/D layout col=lane&15, row=(lane>>4)*4+reg
        int rbase = row0 + wv * 16 + (lane >> 4) * 4;
#pragma unroll
        for (int nt = 0; nt < 8; nt++) {
            int col = nt * 16 + mrow;
            float bv = bias ? bias[col] : 0.f;
            f32x4 v = acc[nt];
#pragma unroll
            for (int reg = 0; reg < 4; reg++) {
                int r2 = rbase + reg;
                if (r2 < M) {
                    float val = v[reg] + bv;
                    if (Cf) Cf[(size_t)r2 * 128 + col] = val;
                    if (Ch) *(f16*)&Ch[(size_t)r2 * 128 + col] = (f16)val;
                }
            }
        }
        if (el) {  // cols 128..135: el heads 0-3, er heads 0-3
            f32x4 v = acc[8];
#pragma unroll
            for (int reg = 0; reg < 4; reg++) {
                int r2 = rbase + reg;
                if (r2 < M) {
                    if (mrow < 4) el[r2 * 4 + mrow] = v[reg];
                    else if (mrow < 8) er[r2 * 4 + (mrow - 4)] = v[reg];
                }
            }
        }
    }
}

__device__ void gemm_sel(const P& p, int which, char* sh) {
    if (which == 1)
        gemm_core(p.features, 0, 256, p.b1, nullptr, nullptr, p.fth, p.el, p.er,
                  p.N, 256, sh);
    else if (which == 2)
        gemm_core(p.xcat, 1, 256, p.b2, nullptr, nullptr, p.fth, p.el, p.er,
                  p.N, 128, sh);
    else
        gemm_core(p.xcat, 1, 256, p.b3, p.bout, p.out, nullptr, nullptr, nullptr,
                  p.N, 256, sh);
}

__device__ __forceinline__ float lrelu(float x) {
    return x > 0.f ? x : NEG_SLOPE * x;
}

__device__ void phase_agg(const P& p, int ooff, char* sh) {
    float4* sA = (float4*)sh;          // [wave*64 + edge] normalized alphas
    int* sS = (int*)(sh + 4096);       // [wave*64 + edge] src node
    const u32* fth2 = (const u32*)p.fth;
    const float4* el4 = (const float4*)p.el;
    const float4* er4 = (const float4*)p.er;
    int wv = threadIdx.x >> 6;
    int lane = threadIdx.x & 63;
    int head = lane >> 4;
    int ngroups = (p.N + 3) >> 2;
    for (int g = blockIdx.x; g < ngroups; g += gridDim.x) {
        int n = g * 4 + wv;
        if (n >= p.N) continue;
        int r0 = p.start[n], deg = p.cnt[n];
        u16* op = &p.xcat[(size_t)n * 256 + ooff + 2 * lane];
        if (deg == 0) {
            *(u32*)op = 0;
            continue;
        }
        float4 ern = er4[n];  // wave-uniform
        float acc0 = 0.f, acc1 = 0.f;
        if (deg <= 64) {
            // lane i owns edge i. Logits tiny (|l| < ~2): softmax w/o max-shift is safe.
            float4 a = make_float4(0.f, 0.f, 0.f, 0.f);
            int s = 0;
            if (lane < deg) {
                int2 ep = p.edge_s[r0 + lane];
                s = ep.x;
                float we = __int_as_float(ep.y);
                float4 e = el4[s];
                a.x = __expf(we * lrelu(e.x + ern.x));
                a.y = __expf(we * lrelu(e.y + ern.y));
                a.z = __expf(we * lrelu(e.z + ern.z));
                a.w = __expf(we * lrelu(e.w + ern.w));
            }
            float4 sm = a;
            for (int m = 1; m < deg; m <<= 1) {  // truncated butterfly
                sm.x += __shfl_xor(sm.x, m);
                sm.y += __shfl_xor(sm.y, m);
                sm.z += __shfl_xor(sm.z, m);
                sm.w += __shfl_xor(sm.w, m);
            }
            a.x *= __builtin_amdgcn_rcpf(sm.x);
            a.y *= __builtin_amdgcn_rcpf(sm.y);
            a.z *= __builtin_amdgcn_rcpf(sm.z);
            a.w *= __builtin_amdgcn_rcpf(sm.w);
            sA[wv * 64 + lane] = a;
            sS[wv * 64 + lane] = s;
            const float* sAf = (const float*)&sA[wv * 64];
            const int* sSp = &sS[wv * 64];
            int i = 0;
            for (; i + 8 <= deg; i += 8) {  // 8 independent gathers in flight
                float wg[8];
                u32 pp[8];
#pragma unroll
                for (int j = 0; j < 8; j++) {
                    wg[j] = sAf[(i + j) * 4 + head];
                    pp[j] = fth2[(size_t)sSp[i + j] * 64 + lane];
                }
#pragma unroll
                for (int j = 0; j < 8; j++) {
                    f16x2 hp = *(const f16x2*)&pp[j];
                    acc0 += wg[j] * (float)hp.x;
                    acc1 += wg[j] * (float)hp.y;
                }
            }
            for (; i < deg; i++) {
                float wgt = sAf[i * 4 + head];
                u32 pv = fth2[(size_t)sSp[i] * 64 + lane];
                f16x2 hp = *(const f16x2*)&pv;
                acc0 += wgt * (float)hp.x;
                acc1 += wgt * (float)hp.y;
            }
        } else {
            // deg > 64 (rare): lane-strided, keep max-shift
            float4 mx = make_float4(-INFINITY, -INFINITY, -INFINITY, -INFINITY);
            for (int i = lane; i < deg; i += 64) {
                int2 ep = p.edge_s[r0 + i];
                float we = __int_as_float(ep.y);
                float4 e = el4[ep.x];
                mx.x = fmaxf(mx.x, we * lrelu(e.x + ern.x));
                mx.y = fmaxf(mx.y, we * lrelu(e.y + ern.y));
                mx.z = fmaxf(mx.z, we * lrelu(e.z + ern.z));
                mx.w = fmaxf(mx.w, we * lrelu(e.w + ern.w));
            }
            for (int m = 32; m >= 1; m >>= 1) {
                mx.x = fmaxf(mx.x, __shfl_xor(mx.x, m));
                mx.y = fmaxf(mx.y, __shfl_xor(mx.y, m));
                mx.z = fmaxf(mx.z, __shfl_xor(mx.z, m));
                mx.w = fmaxf(mx.w, __shfl_xor(mx.w, m));
            }
            float4 sm = make_float4(0.f, 0.f, 0.f, 0.f);
            for (int i = lane; i < deg; i += 64) {
                int2 ep = p.edge_s[r0 + i];
                float we = __int_as_float(ep.y);
                float4 e = el4[ep.x];
                sm.x += __expf(we * lrelu(e.x + ern.x) - mx.x);
                sm.y += __expf(we * lrelu(e.y + ern.y) - mx.y);
                sm.z += __expf(we * lrelu(e.z + ern.z) - mx.z);
                sm.w += __expf(we * lrelu(e.w + ern.w) - mx.w);
            }
            for (int m = 32; m >= 1; m >>= 1) {
                sm.x += __shfl_xor(sm.x, m);
                sm.y += __shfl_xor(sm.y, m);
                sm.z += __shfl_xor(sm.z, m);
                sm.w += __shfl_xor(sm.w, m);
            }
            float4 inv;
            inv.x = 1.f / sm.x; inv.y = 1.f / sm.y;
            inv.z = 1.f / sm.z; inv.w = 1.f / sm.w;
            for (int i = 0; i < deg; i++) {
                int2 ep = p.edge_s[r0 + i];
                int si = ep.x;
                float we = __int_as_float(ep.y);
                float4 e = el4[si];
                float ax = __expf(we * lrelu(e.x + ern.x) - mx.x) * inv.x;
                float ay = __expf(we * lrelu(e.y + ern.y) - mx.y) * inv.y;
                float az = __expf(we * lrelu(e.z + ern.z) - mx.z) * inv.z;
                float aw = __expf(we * lrelu(e.w + ern.w) - mx.w) * inv.w;
                float wgt = head == 0 ? ax : (head == 1 ? ay : (head == 2 ? az : aw));
                u32 pv = fth2[(size_t)si * 64 + lane];
                f16x2 hp = *(const f16x2*)&pv;
                acc0 += wgt * (float)hp.x;
                acc1 += wgt * (float)hp.y;
            }
        }
        f16x2 hv;
        hv.x = (f16)fmaxf(acc0, 0.f);
        hv.y = (f16)fmaxf(acc1, 0.f);
        *(f16x2*)op = hv;
    }
}

// ---------------- fused persistent kernel: 7 phases, 6 grid syncs ----------------

__global__ __launch_bounds__(256, 4) void k_fused(P p) {
    alignas(16) __shared__ char sh[13312];
    phase_hist(p);                  // hist atomics + all weight-panel casts
    gsync(p.bar, 0);
    phase_assign(p, sh);            // segment starts (order-free)
    gsync(p.bar, 1);
    phase_scatter(p);               // edge scatter (independent of gemm1)
    gemm_sel(p, 1, sh);             // fth/el/er = f(features @ W1)
    gsync(p.bar, 2);
    phase_agg(p, 0, sh);            // x1 -> xcat[:, 0:128]
    gsync(p.bar, 3);
    gemm_sel(p, 2, sh);             // fth/el/er = f(x1 @ W2)
    gsync(p.bar, 4);
    phase_agg(p, 128, sh);          // x2 -> xcat[:, 128:256]
    gsync(p.bar, 5);
    gemm_sel(p, 3, sh);             // out = xcat @ Wout + bout
}

// ---------------- fallback wrappers (multi-dispatch path) ----------------

__global__ __launch_bounds__(256) void k_p1(P p) { phase_hist(p); }
__global__ __launch_bounds__(256) void k_assign(P p) {
    alignas(16) __shared__ char sh[2048];
    phase_assign(p, sh);
}
__global__ __launch_bounds__(256) void k_scatter(P p) { phase_scatter(p); }
__global__ __launch_bounds__(256) void k_gemm(P p, int which) {
    alignas(16) __shared__ char sh[13312];
    gemm_sel(p, which, sh);
}
__global__ __launch_bounds__(256) void k_agg(P p, int ooff) {
    alignas(16) __shared__ char sh[8192];
    phase_agg(p, ooff, sh);
}

// ---------------- launch ----------------

extern "C" void kernel_launch(void* const* d_in, const int* in_sizes, int n_in,
                              void* d_out, int out_size, void* d_ws, size_t ws_size,
                              hipStream_t stream) {
    P p;
    p.features = (const float*)d_in[0];
    p.src = (const int*)d_in[1];
    p.dst = (const int*)d_in[2];
    p.w = (const float*)d_in[3];
    p.W1 = (const float*)d_in[4];
    p.al1 = (const float*)d_in[5];
    p.ar1 = (const float*)d_in[6];
    p.W2 = (const float*)d_in[7];
    p.al2 = (const float*)d_in[8];
    p.ar2 = (const float*)d_in[9];
    p.W3 = (const float*)d_in[10];
    p.bout = (const float*)d_in[11];
    p.out = (float*)d_out;

    p.N = in_sizes[0] / 256;                // 50000
    p.E = in_sizes[1];                      // 400000
    p.Mpad = ((p.N + 127) / 128) * 128;     // 50048

    char* ws = (char*)d_ws;
    size_t off = 0;
    auto alloc = [&](size_t bytes) -> void* {
        void* q = ws + off;
        off = (off + bytes + 255) & ~(size_t)255;
        return q;
    };
    size_t Nr = ((size_t)p.N * 4 + 255) & ~(size_t)255;
    p.cnt = (int*)alloc(2 * Nr + 2048);                 // cnt + fill + ctr + bar
    p.fill = (int*)((char*)p.cnt + Nr);
    p.ctr = (int*)((char*)p.cnt + 2 * Nr);
    p.bar = p.ctr + 64;                                 // 6 slots x 128B (cnt|flag lines)
    p.start = (int*)alloc((size_t)p.N * 4);
    p.edge_s = (int2*)alloc((size_t)p.E * 8);
    p.fth = (u16*)alloc((size_t)p.Mpad * 128 * 2);
    p.el = (float*)alloc((size_t)p.N * 4 * 4);
    p.er = (float*)alloc((size_t)p.N * 4 * 4);
    p.xcat = (u16*)alloc((size_t)p.Mpad * 256 * 2);
    p.b1 = (u16*)alloc((size_t)18432 * 4);
    p.b2 = (u16*)alloc((size_t)9216 * 4);
    p.b3 = (u16*)alloc((size_t)18432 * 4);
    (void)ws_size; (void)n_in; (void)out_size;

    (void)hipMemsetAsync(p.cnt, 0, 2 * Nr + 2048, stream);  // also zeroes barrier slots

    static int s_grid = -2;
    if (s_grid == -2) {
        int b = 0;
        hipError_t e = hipOccupancyMaxActiveBlocksPerMultiprocessor(&b, k_fused, 256, 0);
        // MI355X: 256 CUs. Co-residency guaranteed by occupancy result.
        s_grid = (e == hipSuccess && b >= 1) ? (b * 256 < 1024 ? b * 256 : 1024) : 0;
    }

    if (s_grid > 0) {
        k_fused<<<s_grid, 256, 0, stream>>>(p);
    } else {
        int eb = (p.E + 255) / 256;
        int cb = (p.N + 255) / 256;
        int gb = p.Mpad / 64;
        k_p1<<<eb, 256, 0, stream>>>(p);
        k_assign<<<cb, 256, 0, stream>>>(p);
        k_scatter<<<eb, 256, 0, stream>>>(p);
        k_gemm<<<gb, 256, 0, stream>>>(p, 1);
        k_agg<<<2048, 256, 0, stream>>>(p, 0);
        k_gemm<<<gb, 256, 0, stream>>>(p, 2);
        k_agg<<<2048, 256, 0, stream>>>(p, 128);
        k_gemm<<<gb, 256, 0, stream>>>(p, 3);
    }
}

// Round 5
// 247.631 us; speedup vs baseline: 3.2138x; 2.3940x over previous
//
#include <hip/hip_runtime.h>
#include <math.h>

#define NEG_SLOPE 0.1f

typedef unsigned short u16;
typedef unsigned int u32;
typedef _Float16 f16;
typedef f16 f16x2 __attribute__((ext_vector_type(2)));
typedef f16 f16x8 __attribute__((ext_vector_type(8)));
typedef float f32x4 __attribute__((ext_vector_type(4)));

// async 16B global->LDS (lds dest = wave-uniform base + lane*16)
#define GLLDS16(g, l) __builtin_amdgcn_global_load_lds( \
    (const __attribute__((address_space(1))) void*)(g), \
    (__attribute__((address_space(3))) void*)(l), 16, 0, 0)

// ---------------- hist + all weight-panel casts in one dispatch ----------------
// Panel layout (BLOCKED, conflict-free): per 32-k slice kt, per 16-col block nt:
//   u16 index = kt*(NC*256) ... within slice: nt*512 + kg*128 + col*8 + k_in
// -> MFMA B-fragment read of lane l is a LINEAR 16B read. kt slices contiguous,
// so a BK=64 stage is one linear global_load_lds copy of 2 slices.

__device__ __forceinline__ void cast_panel(const float* __restrict__ W,
                                           const float* __restrict__ al,
                                           const float* __restrict__ ar,
                                           u16* __restrict__ bp, int t, int NC) {
    int per_kt = NC * 16;          // u32 per kt slice
    int kt = t / per_kt;
    int rem = t - kt * per_kt;
    int nt = rem >> 8;             // 256 u32 per 16-col block
    int w32 = rem & 255;
    int kg = w32 >> 6;
    int col = (w32 >> 2) & 15;
    int kp = (w32 & 3) * 2;
    int n = nt * 16 + col;
    int k = kt * 32 + kg * 8 + kp;
    float v0 = 0.f, v1 = 0.f;
    if (n < 128) {
        v0 = W[(size_t)k * 128 + n];
        v1 = W[(size_t)(k + 1) * 128 + n];
    } else if (n < 136) {
        const float* av = (n < 132) ? al : ar;
        int h = (n < 132) ? (n - 128) : (n - 132);
        float s0 = 0.f, s1 = 0.f;
        for (int d = 0; d < 32; d++) {
            float a = av[h * 32 + d];
            s0 += W[(size_t)k * 128 + h * 32 + d] * a;
            s1 += W[(size_t)(k + 1) * 128 + h * 32 + d] * a;
        }
        v0 = s0; v1 = s1;
    }
    f16x2 p;
    p.x = (f16)v0; p.y = (f16)v1;
    *(f16x2*)&((u32*)bp)[t] = p;
}

__global__ void histcast_k(const int* __restrict__ dst, int* __restrict__ cnt, int E,
                           const float* __restrict__ W1, const float* __restrict__ al1,
                           const float* __restrict__ ar1, u16* __restrict__ b1,
                           const float* __restrict__ W2, const float* __restrict__ al2,
                           const float* __restrict__ ar2, u16* __restrict__ b2,
                           const float* __restrict__ W3, u16* __restrict__ b3) {
    int t = blockIdx.x * 256 + threadIdx.x;
    if (t < E) atomicAdd(&cnt[dst[t]], 1);
    // b1: 8 kt * 2304 = 18432 u32; b2: 4 * 2304 = 9216; b3: 8 * 2048 = 16384
    if (t < 18432) cast_panel(W1, al1, ar1, b1, t, 144);
    else if (t < 27648) cast_panel(W2, al2, ar2, b2, t - 18432, 144);
    else if (t < 44032) cast_panel(W3, nullptr, nullptr, b3, t - 27648, 128);
}

// ---------------- segment assignment: start[n] via block scan + one atomic ----------------

__global__ void assign_k(const int* __restrict__ cnt, int* __restrict__ start,
                         int* __restrict__ ctr, int N) {
    __shared__ int s[256];
    __shared__ int base;
    int t = threadIdx.x;
    int i = blockIdx.x * 256 + t;
    int v = (i < N) ? cnt[i] : 0;
    s[t] = v;
    __syncthreads();
    int incl = v;
    for (int off = 1; off < 256; off <<= 1) {
        int add = (t >= off) ? s[t - off] : 0;
        __syncthreads();
        incl += add;
        s[t] = incl;
        __syncthreads();
    }
    if (t == 255) base = atomicAdd(ctr, incl);
    __syncthreads();
    if (i < N) start[i] = base + incl - v;
}

// ---------------- BK=64 fp16 MFMA GEMM tile (device body) ----------------
// Tile 64 rows x (16*NT) cols; per K-step stage 2 contiguous 32-k slices.
// Blocked LDS layout -> all ds_read_b128 / global_load_lds linear, conflict-free.

template <int NT>
__device__ __forceinline__ void gemm_tile(
        const void* __restrict__ Av, int a_is_f16, int lda,
        const u16* __restrict__ Bp,
        const float* __restrict__ bias, float* __restrict__ Cf,
        u16* __restrict__ Ch, float* __restrict__ el, float* __restrict__ er,
        int M, int K, int tile, char* shmem) {
    u16* As = (u16*)shmem;                  // 2 slices * 2048 u16 (64r x 32k blocked)
    u16* Bs = (u16*)(shmem + 8192);         // 2 slices * NT*512 u16
    int tid = threadIdx.x;
    int wv = tid >> 6, lane = tid & 63;
    int mrow = lane & 15;
    int row0 = tile * 64;

    f32x4 acc[NT];
#pragma unroll
    for (int nt = 0; nt < NT; nt++) acc[nt] = (f32x4){0.f, 0.f, 0.f, 0.f};

    for (int k0 = 0; k0 < K; k0 += 64) {
        int kt0 = k0 >> 5;
        // B: 2*NT*64 chunks of 16B, linear copy (slices contiguous in panel)
        const u16* Bsrc = Bp + (size_t)kt0 * (NT * 512);
#pragma unroll
        for (int i = 0; i < (2 * NT * 64 + 255) / 256; i++) {
            int c = tid + i * 256;
            if (c < 2 * NT * 64) GLLDS16(Bsrc + (size_t)c * 8, &Bs[c * 8]);
        }
        // A: 512 chunks, 2 per thread
#pragma unroll
        for (int i = 0; i < 2; i++) {
            int c = tid + i * 256;
            int slice = c >> 8, w32 = c & 255;
            int rblk = w32 >> 6, kg = (w32 >> 4) & 3, rr = w32 & 15;
            int row = row0 + rblk * 16 + rr;
            int k = k0 + slice * 32 + kg * 8;
            if (a_is_f16) {
                const u16* Ah = (const u16*)Av;
                GLLDS16(Ah + (size_t)row * lda + k, &As[c * 8]);
            } else {
                const float* Af = (const float*)Av;
                if (row > M - 1) row = M - 1;  // clamp; pad rows discarded in epilogue
                const float* ap = &Af[(size_t)row * lda + k];
                float4 v0 = *(const float4*)ap;
                float4 v1 = *(const float4*)(ap + 4);
                f16x8 pk;
                pk[0] = (f16)v0.x; pk[1] = (f16)v0.y; pk[2] = (f16)v0.z; pk[3] = (f16)v0.w;
                pk[4] = (f16)v1.x; pk[5] = (f16)v1.y; pk[6] = (f16)v1.z; pk[7] = (f16)v1.w;
                *(f16x8*)&As[c * 8] = pk;
            }
        }
        __syncthreads();
#pragma unroll
        for (int kk = 0; kk < 2; kk++) {
            f16x8 ah = *(const f16x8*)&As[kk * 2048 + wv * 512 + lane * 8];
#pragma unroll
            for (int nt = 0; nt < NT; nt++) {
                f16x8 bh = *(const f16x8*)&Bs[kk * (NT * 512) + nt * 512 + lane * 8];
                acc[nt] = __builtin_amdgcn_mfma_f32_16x16x32_f16(ah, bh, acc[nt], 0, 0, 0);
            }
        }
        __syncthreads();
    }

    // epilogue: C/D layout col=lane&15, row=(lane>>4)*4+reg
    int rbase = row0 + wv * 16 + (lane >> 4) * 4;
#pragma unroll
    for (int nt = 0; nt < 8; nt++) {
        int col = nt * 16 + mrow;
        float bv = bias ? bias[col] : 0.f;
        f32x4 v = acc[nt];
#pragma unroll
        for (int reg = 0; reg < 4; reg++) {
            int rr = rbase + reg;
            if (rr < M) {
                float val = v[reg] + bv;
                if (Cf) Cf[(size_t)rr * 128 + col] = val;
                if (Ch) *(f16*)&Ch[(size_t)rr * 128 + col] = (f16)val;
            }
        }
    }
    if (NT == 9) {  // cols 128..135: el heads 0-3, er heads 0-3
        f32x4 v = acc[8];
#pragma unroll
        for (int reg = 0; reg < 4; reg++) {
            int rr = rbase + reg;
            if (rr < M) {
                if (mrow < 4) el[rr * 4 + mrow] = v[reg];
                else if (mrow < 8) er[rr * 4 + (mrow - 4)] = v[reg];
            }
        }
    }
}

// plain GEMM dispatch (layers 2 & 3)
template <int NT>
__global__ __launch_bounds__(256) void gemm_k(
        const void* __restrict__ Av, int a_is_f16, int lda,
        const u16* __restrict__ Bp, const float* __restrict__ bias,
        float* __restrict__ Cf, u16* __restrict__ Ch,
        float* __restrict__ el, float* __restrict__ er, int M, int K) {
    alignas(16) __shared__ char sh[8192 + NT * 2048];
    gemm_tile<NT>(Av, a_is_f16, lda, Bp, bias, Cf, Ch, el, er, M, K, blockIdx.x, sh);
}

// merged dispatch: blocks [0,gb) = layer-1 GEMM; blocks [gb, gb+eb) = edge scatter.
// scatter (latency-bound atomics) overlaps gemm1 (MFMA/LDS-bound) — independent work.
__global__ __launch_bounds__(256) void g1s_k(
        const float* __restrict__ features, const u16* __restrict__ b1,
        u16* __restrict__ fth, float* __restrict__ el, float* __restrict__ er,
        int M, int gb,
        const int* __restrict__ src, const int* __restrict__ dst,
        const float* __restrict__ w, const int* __restrict__ start,
        int* __restrict__ fill, int2* __restrict__ edge_s, int E) {
    alignas(16) __shared__ char sh[8192 + 9 * 2048];
    if ((int)blockIdx.x < gb) {
        gemm_tile<9>(features, 0, 256, b1, nullptr, nullptr, fth, el, er,
                     M, 256, blockIdx.x, sh);
    } else {
        int e = (blockIdx.x - gb) * 256 + threadIdx.x;
        if (e < E) {
            int d = dst[e];
            int pos = atomicAdd(&fill[d], 1);
            edge_s[start[d] + pos] = make_int2(src[e], __float_as_int(w[e]));
        }
    }
}

// ---------------- fused logits + softmax + aggregation ----------------
// lane covers feature dims 2*lane, 2*lane+1; head = lane>>4. fp16 into concat buffer.
// Grid-stride over node-quads (2048 co-resident blocks).

__device__ __forceinline__ float lrelu(float x) {
    return x > 0.f ? x : NEG_SLOPE * x;
}

__global__ __launch_bounds__(256) void agg_k(const u32* __restrict__ fth2,
                                             const float4* __restrict__ el4,
                                             const float4* __restrict__ er4,
                                             const int2* __restrict__ edge_s,
                                             const int* __restrict__ start,
                                             const int* __restrict__ cnt,
                                             u16* __restrict__ xcat,
                                             int ooff, int N, int ngroups) {
    __shared__ float4 sA[256];  // [wave*64 + edge] normalized alphas
    __shared__ int sS[256];     // [wave*64 + edge] src node
    int wv = threadIdx.x >> 6;
    int lane = threadIdx.x & 63;
    int head = lane >> 4;
    for (int g = blockIdx.x; g < ngroups; g += gridDim.x) {
        int n = g * 4 + wv;
        if (n >= N) continue;
        int r0 = start[n], deg = cnt[n];
        u16* op = &xcat[(size_t)n * 256 + ooff + 2 * lane];
        if (deg == 0) {
            *(u32*)op = 0;
            continue;
        }
        float4 ern = er4[n];  // wave-uniform
        float acc0 = 0.f, acc1 = 0.f;
        if (deg <= 64) {
            // lane i owns edge i. Logits tiny (|l| < ~2): softmax w/o max-shift safe.
            float4 a = make_float4(0.f, 0.f, 0.f, 0.f);
            int s = 0;
            if (lane < deg) {
                int2 ep = edge_s[r0 + lane];
                s = ep.x;
                float we = __int_as_float(ep.y);
                float4 e = el4[s];
                a.x = __expf(we * lrelu(e.x + ern.x));
                a.y = __expf(we * lrelu(e.y + ern.y));
                a.z = __expf(we * lrelu(e.z + ern.z));
                a.w = __expf(we * lrelu(e.w + ern.w));
            }
            float4 sm = a;
            for (int m = 1; m < deg; m <<= 1) {  // truncated butterfly
                sm.x += __shfl_xor(sm.x, m);
                sm.y += __shfl_xor(sm.y, m);
                sm.z += __shfl_xor(sm.z, m);
                sm.w += __shfl_xor(sm.w, m);
            }
            a.x *= __builtin_amdgcn_rcpf(sm.x);
            a.y *= __builtin_amdgcn_rcpf(sm.y);
            a.z *= __builtin_amdgcn_rcpf(sm.z);
            a.w *= __builtin_amdgcn_rcpf(sm.w);
            sA[wv * 64 + lane] = a;
            sS[wv * 64 + lane] = s;
            const float* sAf = (const float*)&sA[wv * 64];
            const int* sSp = &sS[wv * 64];
            int i = 0;
            for (; i + 8 <= deg; i += 8) {  // 8 independent gathers in flight
                float wg[8];
                u32 pp[8];
#pragma unroll
                for (int j = 0; j < 8; j++) {
                    wg[j] = sAf[(i + j) * 4 + head];
                    pp[j] = fth2[(size_t)sSp[i + j] * 64 + lane];
                }
#pragma unroll
                for (int j = 0; j < 8; j++) {
                    f16x2 hp = *(const f16x2*)&pp[j];
                    acc0 += wg[j] * (float)hp.x;
                    acc1 += wg[j] * (float)hp.y;
                }
            }
            for (; i < deg; i++) {
                float wgt = sAf[i * 4 + head];
                u32 p = fth2[(size_t)sSp[i] * 64 + lane];
                f16x2 hp = *(const f16x2*)&p;
                acc0 += wgt * (float)hp.x;
                acc1 += wgt * (float)hp.y;
            }
        } else {
            // deg > 64 (rare): lane-strided, keep max-shift
            float4 mx = make_float4(-INFINITY, -INFINITY, -INFINITY, -INFINITY);
            for (int i = lane; i < deg; i += 64) {
                int2 ep = edge_s[r0 + i];
                float we = __int_as_float(ep.y);
                float4 e = el4[ep.x];
                mx.x = fmaxf(mx.x, we * lrelu(e.x + ern.x));
                mx.y = fmaxf(mx.y, we * lrelu(e.y + ern.y));
                mx.z = fmaxf(mx.z, we * lrelu(e.z + ern.z));
                mx.w = fmaxf(mx.w, we * lrelu(e.w + ern.w));
            }
            for (int m = 32; m >= 1; m >>= 1) {
                mx.x = fmaxf(mx.x, __shfl_xor(mx.x, m));
                mx.y = fmaxf(mx.y, __shfl_xor(mx.y, m));
                mx.z = fmaxf(mx.z, __shfl_xor(mx.z, m));
                mx.w = fmaxf(mx.w, __shfl_xor(mx.w, m));
            }
            float4 sm = make_float4(0.f, 0.f, 0.f, 0.f);
            for (int i = lane; i < deg; i += 64) {
                int2 ep = edge_s[r0 + i];
                float we = __int_as_float(ep.y);
                float4 e = el4[ep.x];
                sm.x += __expf(we * lrelu(e.x + ern.x) - mx.x);
                sm.y += __expf(we * lrelu(e.y + ern.y) - mx.y);
                sm.z += __expf(we * lrelu(e.z + ern.z) - mx.z);
                sm.w += __expf(we * lrelu(e.w + ern.w) - mx.w);
            }
            for (int m = 32; m >= 1; m >>= 1) {
                sm.x += __shfl_xor(sm.x, m);
                sm.y += __shfl_xor(sm.y, m);
                sm.z += __shfl_xor(sm.z, m);
                sm.w += __shfl_xor(sm.w, m);
            }
            float4 inv;
            inv.x = 1.f / sm.x; inv.y = 1.f / sm.y;
            inv.z = 1.f / sm.z; inv.w = 1.f / sm.w;
            for (int i = 0; i < deg; i++) {
                int2 ep = edge_s[r0 + i];
                int si = ep.x;
                float we = __int_as_float(ep.y);
                float4 e = el4[si];
                float ax = __expf(we * lrelu(e.x + ern.x) - mx.x) * inv.x;
                float ay = __expf(we * lrelu(e.y + ern.y) - mx.y) * inv.y;
                float az = __expf(we * lrelu(e.z + ern.z) - mx.z) * inv.z;
                float aw = __expf(we * lrelu(e.w + ern.w) - mx.w) * inv.w;
                float wgt = head == 0 ? ax : (head == 1 ? ay : (head == 2 ? az : aw));
                u32 p = fth2[(size_t)si * 64 + lane];
                f16x2 hp = *(const f16x2*)&p;
                acc0 += wgt * (float)hp.x;
                acc1 += wgt * (float)hp.y;
            }
        }
        f16x2 hv;
        hv.x = (f16)fmaxf(acc0, 0.f);
        hv.y = (f16)fmaxf(acc1, 0.f);
        *(f16x2*)op = hv;
    }
}

// ---------------- launch ----------------

extern "C" void kernel_launch(void* const* d_in, const int* in_sizes, int n_in,
                              void* d_out, int out_size, void* d_ws, size_t ws_size,
                              hipStream_t stream) {
    const float* features = (const float*)d_in[0];
    const int* src = (const int*)d_in[1];
    const int* dst = (const int*)d_in[2];
    const float* w = (const float*)d_in[3];
    const float* W1 = (const float*)d_in[4];
    const float* al1 = (const float*)d_in[5];
    const float* ar1 = (const float*)d_in[6];
    const float* W2 = (const float*)d_in[7];
    const float* al2 = (const float*)d_in[8];
    const float* ar2 = (const float*)d_in[9];
    const float* Wout = (const float*)d_in[10];
    const float* bout = (const float*)d_in[11];
    float* out = (float*)d_out;

    int N = in_sizes[0] / 256;           // 50000
    int E = in_sizes[1];                 // 400000
    int Mpad = ((N + 127) / 128) * 128;  // 50048

    char* ws = (char*)d_ws;
    size_t off = 0;
    auto alloc = [&](size_t bytes) -> void* {
        void* p = ws + off;
        off = (off + bytes + 255) & ~(size_t)255;
        return p;
    };
    size_t Nr = ((size_t)N * 4 + 255) & ~(size_t)255;
    int* cnt = (int*)alloc(2 * Nr + 256);            // cnt + fill + ctr, single memset
    int* fill = (int*)((char*)cnt + Nr);
    int* ctr = (int*)((char*)cnt + 2 * Nr);
    int* start = (int*)alloc((size_t)N * 4);
    int2* edge_s = (int2*)alloc((size_t)E * 8);
    u16* fth = (u16*)alloc((size_t)Mpad * 128 * 2);   // fp16 node features (per layer)
    float* el = (float*)alloc((size_t)N * 4 * 4);
    float* er = (float*)alloc((size_t)N * 4 * 4);
    u16* xcat = (u16*)alloc((size_t)Mpad * 256 * 2);  // concat(x1,x2) fp16
    u16* b1 = (u16*)alloc((size_t)18432 * 4);         // 144-col panel, K=256
    u16* b2 = (u16*)alloc((size_t)9216 * 4);          // 144-col panel, K=128
    u16* b3 = (u16*)alloc((size_t)16384 * 4);         // 128-col panel, K=256
    (void)ws_size; (void)n_in; (void)out_size;

    (void)hipMemsetAsync(cnt, 0, 2 * Nr + 256, stream);

    int eb = (E + 255) / 256;
    int nb = (N + 255) / 256;
    int ng = (N + 3) / 4;                // node-quads
    int ab = ng < 2048 ? ng : 2048;      // co-resident grid, grid-stride loop
    int gb = Mpad / 64;                  // 782 tiles (64-row)

    // CSR-ish build + weight panels
    histcast_k<<<eb, 256, 0, stream>>>(dst, cnt, E, W1, al1, ar1, b1,
                                       W2, al2, ar2, b2, Wout, b3);
    assign_k<<<nb, 256, 0, stream>>>(cnt, start, ctr, N);

    // layer-1 GEMM (fp32 A, fused el/er) overlapped with edge scatter
    g1s_k<<<gb + eb, 256, 0, stream>>>(features, b1, fth, el, er, N, gb,
                                       src, dst, w, start, fill, edge_s, E);
    agg_k<<<ab, 256, 0, stream>>>((const u32*)fth, (const float4*)el, (const float4*)er,
                                  edge_s, start, cnt, xcat, 0, N, ng);

    // layer 2: fth = fp16(x1 @ W2)
    gemm_k<9><<<gb, 256, 0, stream>>>(xcat, 1, 256, b2, nullptr,
                                      nullptr, fth, el, er, N, 128);
    agg_k<<<ab, 256, 0, stream>>>((const u32*)fth, (const float4*)el, (const float4*)er,
                                  edge_s, start, cnt, xcat, 128, N, ng);

    // output GEMM: out = xcat @ Wout + bout
    gemm_k<8><<<gb, 256, 0, stream>>>(xcat, 1, 256, b3, bout,
                                      out, nullptr, nullptr, nullptr, N, 256);
}